// Round 2
// baseline (880.557 us; speedup 1.0000x reference)
//
#include <hip/hip_runtime.h>

#define N_NODES 100000
#define N_EDGES 1600000
#define IN_DIM 256
#define OUT_DIM 32

#define GEMM_ROWS 128
#define GEMM_KC 64

// ---------------------------------------------------------------------------
// Phase 1: degree computation (int atomics)
// ---------------------------------------------------------------------------
__global__ __launch_bounds__(256) void k_degree(const int* __restrict__ src,
                                                const int* __restrict__ dst,
                                                int* __restrict__ deg_out,
                                                int* __restrict__ deg_in) {
    int i = blockIdx.x * 256 + threadIdx.x;
    if (i < N_EDGES) {
        atomicAdd(&deg_out[src[i]], 1);
        atomicAdd(&deg_in[dst[i]], 1);
    }
}

// ---------------------------------------------------------------------------
// Phase 2: h = (x * norm_src) @ W   [100000,256]x[256,32] -> [100000,32]
// Block: 256 threads, 128 rows per block, K staged in 64-wide chunks.
// Thread tile: 4 rows x 4 cols (16 f32 accumulators).
// LDS: W[256][32] = 32 KB, xs[128][68] = 34 KB.
// ---------------------------------------------------------------------------
__global__ __launch_bounds__(256) void k_gemm(const float* __restrict__ x,
                                              const float* __restrict__ W,
                                              const int* __restrict__ deg_out,
                                              float* __restrict__ h) {
    __shared__ float Wl[IN_DIM][OUT_DIM];        // 32 KB
    __shared__ float xs[GEMM_ROWS][GEMM_KC + 4]; // 34816 B

    const int tid = threadIdx.x;
    const int row0 = blockIdx.x * GEMM_ROWS;

    // load W into LDS (8192 floats, 32 per thread, coalesced)
    #pragma unroll
    for (int i = 0; i < (IN_DIM * OUT_DIM) / 256; ++i) {
        int idx = tid + i * 256;
        Wl[idx >> 5][idx & 31] = W[idx];
    }

    const int cg = tid & 7;   // col group 0..7
    const int rg = tid >> 3;  // row group 0..31
    const int co = cg * 4;    // first col of thread tile
    const int ro = rg * 4;    // first row (within block tile)

    float acc[4][4];
    #pragma unroll
    for (int r = 0; r < 4; ++r)
        #pragma unroll
        for (int c = 0; c < 4; ++c) acc[r][c] = 0.f;

    for (int kc = 0; kc < IN_DIM; kc += GEMM_KC) {
        if (kc) __syncthreads();  // xs reuse from previous chunk

        // stage 128 rows x 64 k = 2048 float4, 8 per thread, coalesced,
        // norm_src applied at staging time
        #pragma unroll
        for (int j = 0; j < 8; ++j) {
            int f = tid + j * 256;   // 0..2047
            int r = f >> 4;          // row in tile (16 float4 per row-chunk)
            int k4 = f & 15;
            int grow = row0 + r;
            float4 v = make_float4(0.f, 0.f, 0.f, 0.f);
            if (grow < N_NODES) {
                v = *reinterpret_cast<const float4*>(
                    &x[(size_t)grow * IN_DIM + kc + k4 * 4]);
                int dg = deg_out[grow];
                float nrm = rsqrtf((float)(dg > 1 ? dg : 1));
                v.x *= nrm; v.y *= nrm; v.z *= nrm; v.w *= nrm;
            }
            *reinterpret_cast<float4*>(&xs[r][k4 * 4]) = v;
        }
        __syncthreads();  // also covers initial W load

        #pragma unroll
        for (int k4 = 0; k4 < GEMM_KC / 4; ++k4) {
            // FIX R1: W row index must include the K-chunk offset kc
            float4 w0 = *reinterpret_cast<const float4*>(&Wl[kc + k4 * 4 + 0][co]);
            float4 w1 = *reinterpret_cast<const float4*>(&Wl[kc + k4 * 4 + 1][co]);
            float4 w2 = *reinterpret_cast<const float4*>(&Wl[kc + k4 * 4 + 2][co]);
            float4 w3 = *reinterpret_cast<const float4*>(&Wl[kc + k4 * 4 + 3][co]);
            #pragma unroll
            for (int r = 0; r < 4; ++r) {
                float4 xv = *reinterpret_cast<const float4*>(&xs[ro + r][k4 * 4]);
                acc[r][0] += xv.x * w0.x + xv.y * w1.x + xv.z * w2.x + xv.w * w3.x;
                acc[r][1] += xv.x * w0.y + xv.y * w1.y + xv.z * w2.y + xv.w * w3.y;
                acc[r][2] += xv.x * w0.z + xv.y * w1.z + xv.z * w2.z + xv.w * w3.z;
                acc[r][3] += xv.x * w0.w + xv.y * w1.w + xv.z * w2.w + xv.w * w3.w;
            }
        }
    }

    #pragma unroll
    for (int r = 0; r < 4; ++r) {
        int grow = row0 + ro + r;
        if (grow < N_NODES) {
            float4 v = make_float4(acc[r][0], acc[r][1], acc[r][2], acc[r][3]);
            *reinterpret_cast<float4*>(&h[(size_t)grow * OUT_DIM + co]) = v;
        }
    }
}

// ---------------------------------------------------------------------------
// Phase 3: scatter msgs = h[src] into out[dst] (f32 atomics)
// 8 threads per edge, each owns 4 consecutive cols (float4 gather of h).
// ---------------------------------------------------------------------------
__global__ __launch_bounds__(256) void k_scatter(const int* __restrict__ src,
                                                 const int* __restrict__ dst,
                                                 const float* __restrict__ h,
                                                 float* __restrict__ out) {
    int t = blockIdx.x * 256 + threadIdx.x;
    if (t >= N_EDGES * 8) return;
    int e = t >> 3;
    int c4 = (t & 7) << 2;
    int s = src[e];
    int d = dst[e];
    float4 v = *reinterpret_cast<const float4*>(&h[(size_t)s * OUT_DIM + c4]);
    float* o = out + (size_t)d * OUT_DIM + c4;
    atomicAdd(o + 0, v.x);
    atomicAdd(o + 1, v.y);
    atomicAdd(o + 2, v.z);
    atomicAdd(o + 3, v.w);
}

// ---------------------------------------------------------------------------
// Phase 4: out = out * norm_dst + b
// ---------------------------------------------------------------------------
__global__ __launch_bounds__(256) void k_finalize(float* __restrict__ out,
                                                  const int* __restrict__ deg_in,
                                                  const float* __restrict__ bias) {
    int i4 = blockIdx.x * 256 + threadIdx.x;  // float4 index
    if (i4 >= N_NODES * 8) return;
    int node = i4 >> 3;
    int c4 = (i4 & 7) << 2;
    int dg = deg_in[node];
    float nrm = rsqrtf((float)(dg > 1 ? dg : 1));
    float4 v = *reinterpret_cast<float4*>(out + (size_t)i4 * 4);
    float4 bb = *reinterpret_cast<const float4*>(&bias[c4]);
    v.x = v.x * nrm + bb.x;
    v.y = v.y * nrm + bb.y;
    v.z = v.z * nrm + bb.z;
    v.w = v.w * nrm + bb.w;
    *reinterpret_cast<float4*>(out + (size_t)i4 * 4) = v;
}

// ---------------------------------------------------------------------------
extern "C" void kernel_launch(void* const* d_in, const int* in_sizes, int n_in,
                              void* d_out, int out_size, void* d_ws, size_t ws_size,
                              hipStream_t stream) {
    const float* x   = (const float*)d_in[0];
    const int*   src = (const int*)d_in[1];
    const int*   dst = (const int*)d_in[2];
    const float* W   = (const float*)d_in[3];
    const float* b   = (const float*)d_in[4];
    float* out = (float*)d_out;

    // workspace layout: deg_out int[N] | deg_in int[N] | h float[N*32]
    int* deg_out = (int*)d_ws;
    int* deg_in  = deg_out + N_NODES;
    float* h     = (float*)(deg_in + N_NODES);  // byte offset 800000 (16B aligned)

    hipMemsetAsync(d_ws, 0, 2 * N_NODES * sizeof(int), stream);
    hipMemsetAsync(d_out, 0, (size_t)out_size * sizeof(float), stream);

    k_degree<<<(N_EDGES + 255) / 256, 256, 0, stream>>>(src, dst, deg_out, deg_in);

    k_gemm<<<(N_NODES + GEMM_ROWS - 1) / GEMM_ROWS, 256, 0, stream>>>(x, W, deg_out, h);

    k_scatter<<<(N_EDGES * 8 + 255) / 256, 256, 0, stream>>>(src, dst, h, out);

    k_finalize<<<(N_NODES * 8 + 255) / 256, 256, 0, stream>>>(out, deg_in, b);
}

// Round 3
// 421.607 us; speedup vs baseline: 2.0886x; 2.0886x over previous
//
#include <hip/hip_runtime.h>

#define N_NODES 100000
#define N_EDGES 1600000
#define IN_DIM 256
#define OUT_DIM 32

#define GEMM_ROWS 128
#define GEMM_KC 64

#define SCAN_BLK 256
#define NBLK ((N_NODES + SCAN_BLK - 1) / SCAN_BLK)   // 391

// ---------------------------------------------------------------------------
// Phase 1: degree computation (int atomics)
// ---------------------------------------------------------------------------
__global__ __launch_bounds__(256) void k_degree(const int* __restrict__ src,
                                                const int* __restrict__ dst,
                                                int* __restrict__ deg_out,
                                                int* __restrict__ deg_in) {
    int i = blockIdx.x * 256 + threadIdx.x;
    if (i < N_EDGES) {
        atomicAdd(&deg_out[src[i]], 1);
        atomicAdd(&deg_in[dst[i]], 1);
    }
}

// ---------------------------------------------------------------------------
// Phase 2: h = (x * norm_src) @ W
// ---------------------------------------------------------------------------
__global__ __launch_bounds__(256) void k_gemm(const float* __restrict__ x,
                                              const float* __restrict__ W,
                                              const int* __restrict__ deg_out,
                                              float* __restrict__ h) {
    __shared__ float Wl[IN_DIM][OUT_DIM];        // 32 KB
    __shared__ float xs[GEMM_ROWS][GEMM_KC + 4]; // 34816 B

    const int tid = threadIdx.x;
    const int row0 = blockIdx.x * GEMM_ROWS;

    #pragma unroll
    for (int i = 0; i < (IN_DIM * OUT_DIM) / 256; ++i) {
        int idx = tid + i * 256;
        Wl[idx >> 5][idx & 31] = W[idx];
    }

    const int cg = tid & 7;
    const int rg = tid >> 3;
    const int co = cg * 4;
    const int ro = rg * 4;

    float acc[4][4];
    #pragma unroll
    for (int r = 0; r < 4; ++r)
        #pragma unroll
        for (int c = 0; c < 4; ++c) acc[r][c] = 0.f;

    for (int kc = 0; kc < IN_DIM; kc += GEMM_KC) {
        if (kc) __syncthreads();

        #pragma unroll
        for (int j = 0; j < 8; ++j) {
            int f = tid + j * 256;
            int r = f >> 4;
            int k4 = f & 15;
            int grow = row0 + r;
            float4 v = make_float4(0.f, 0.f, 0.f, 0.f);
            if (grow < N_NODES) {
                v = *reinterpret_cast<const float4*>(
                    &x[(size_t)grow * IN_DIM + kc + k4 * 4]);
                int dg = deg_out[grow];
                float nrm = rsqrtf((float)(dg > 1 ? dg : 1));
                v.x *= nrm; v.y *= nrm; v.z *= nrm; v.w *= nrm;
            }
            *reinterpret_cast<float4*>(&xs[r][k4 * 4]) = v;
        }
        __syncthreads();

        #pragma unroll
        for (int k4 = 0; k4 < GEMM_KC / 4; ++k4) {
            float4 w0 = *reinterpret_cast<const float4*>(&Wl[kc + k4 * 4 + 0][co]);
            float4 w1 = *reinterpret_cast<const float4*>(&Wl[kc + k4 * 4 + 1][co]);
            float4 w2 = *reinterpret_cast<const float4*>(&Wl[kc + k4 * 4 + 2][co]);
            float4 w3 = *reinterpret_cast<const float4*>(&Wl[kc + k4 * 4 + 3][co]);
            #pragma unroll
            for (int r = 0; r < 4; ++r) {
                float4 xv = *reinterpret_cast<const float4*>(&xs[ro + r][k4 * 4]);
                acc[r][0] += xv.x * w0.x + xv.y * w1.x + xv.z * w2.x + xv.w * w3.x;
                acc[r][1] += xv.x * w0.y + xv.y * w1.y + xv.z * w2.y + xv.w * w3.y;
                acc[r][2] += xv.x * w0.z + xv.y * w1.z + xv.z * w2.z + xv.w * w3.z;
                acc[r][3] += xv.x * w0.w + xv.y * w1.w + xv.z * w2.w + xv.w * w3.w;
            }
        }
    }

    #pragma unroll
    for (int r = 0; r < 4; ++r) {
        int grow = row0 + ro + r;
        if (grow < N_NODES) {
            float4 v = make_float4(acc[r][0], acc[r][1], acc[r][2], acc[r][3]);
            *reinterpret_cast<float4*>(&h[(size_t)grow * OUT_DIM + co]) = v;
        }
    }
}

// ---------------------------------------------------------------------------
// Phase 3a: exclusive prefix sum of deg_in -> row_ptr (3-kernel scan)
// ---------------------------------------------------------------------------
__global__ __launch_bounds__(SCAN_BLK) void k_scan1(const int* __restrict__ deg_in,
                                                    int* __restrict__ row_ptr,
                                                    int* __restrict__ partial) {
    __shared__ int s[SCAN_BLK];
    int tid = threadIdx.x;
    int i = blockIdx.x * SCAN_BLK + tid;
    int v = (i < N_NODES) ? deg_in[i] : 0;
    s[tid] = v;
    __syncthreads();
    #pragma unroll
    for (int off = 1; off < SCAN_BLK; off <<= 1) {
        int t = (tid >= off) ? s[tid - off] : 0;
        __syncthreads();
        s[tid] += t;
        __syncthreads();
    }
    if (i < N_NODES) row_ptr[i] = s[tid] - v;   // exclusive within block
    if (tid == SCAN_BLK - 1) partial[blockIdx.x] = s[tid];
}

__global__ __launch_bounds__(512) void k_scan2(int* __restrict__ partial) {
    __shared__ int s[512];
    int tid = threadIdx.x;
    int v = (tid < NBLK) ? partial[tid] : 0;
    s[tid] = v;
    __syncthreads();
    #pragma unroll
    for (int off = 1; off < 512; off <<= 1) {
        int t = (tid >= off) ? s[tid - off] : 0;
        __syncthreads();
        s[tid] += t;
        __syncthreads();
    }
    if (tid < NBLK) partial[tid] = s[tid] - v;  // exclusive block offsets
}

__global__ __launch_bounds__(SCAN_BLK) void k_scan3(int* __restrict__ row_ptr,
                                                    const int* __restrict__ partial) {
    int i = blockIdx.x * SCAN_BLK + threadIdx.x;
    if (i < N_NODES) row_ptr[i] += partial[blockIdx.x];
}

// ---------------------------------------------------------------------------
// Phase 3b: bucket edges by dst (counting sort payload = src index)
// ---------------------------------------------------------------------------
__global__ __launch_bounds__(256) void k_bucket(const int* __restrict__ src,
                                                const int* __restrict__ dst,
                                                const int* __restrict__ row_ptr,
                                                int* __restrict__ cursor,
                                                int* __restrict__ esrc) {
    int e = blockIdx.x * 256 + threadIdx.x;
    if (e < N_EDGES) {
        int d = dst[e];
        int pos = row_ptr[d] + atomicAdd(&cursor[d], 1);
        esrc[pos] = src[e];
    }
}

// ---------------------------------------------------------------------------
// Phase 4: pull-based aggregate + finalize (fused)
// One wave per node: 32 lanes = 32 cols; the two 32-lane halves process
// alternating edges (2 independent load chains), combined via shfl_xor(32).
// ---------------------------------------------------------------------------
__global__ __launch_bounds__(256) void k_gather(const int* __restrict__ esrc,
                                                const int* __restrict__ row_ptr,
                                                const int* __restrict__ deg_in,
                                                const float* __restrict__ h,
                                                const float* __restrict__ bias,
                                                float* __restrict__ out) {
    int wave = (blockIdx.x * 256 + threadIdx.x) >> 6;
    if (wave >= N_NODES) return;
    int lane = threadIdx.x & 63;
    int c = lane & 31;
    int half = lane >> 5;

    int start = row_ptr[wave];
    int deg = deg_in[wave];

    float acc = 0.f;
    for (int j = half; j < deg; j += 2) {
        int s = esrc[start + j];
        acc += h[(size_t)s * OUT_DIM + c];
    }
    acc += __shfl_xor(acc, 32);

    if (half == 0) {
        float nrm = rsqrtf((float)(deg > 1 ? deg : 1));
        out[(size_t)wave * OUT_DIM + c] = acc * nrm + bias[c];
    }
}

// ---------------------------------------------------------------------------
extern "C" void kernel_launch(void* const* d_in, const int* in_sizes, int n_in,
                              void* d_out, int out_size, void* d_ws, size_t ws_size,
                              hipStream_t stream) {
    const float* x   = (const float*)d_in[0];
    const int*   src = (const int*)d_in[1];
    const int*   dst = (const int*)d_in[2];
    const float* W   = (const float*)d_in[3];
    const float* b   = (const float*)d_in[4];
    float* out = (float*)d_out;

    // ws layout (ints): deg_out[N] deg_in[N] row_ptr[N] cursor[N] partial[512]
    //                   then h float[N*32], esrc int[E]
    int* deg_out = (int*)d_ws;
    int* deg_in  = deg_out + N_NODES;
    int* row_ptr = deg_in + N_NODES;
    int* cursor  = row_ptr + N_NODES;
    int* partial = cursor + N_NODES;
    float* h     = (float*)(partial + 512);       // int offset 400512 (16B-aligned)
    int* esrc    = (int*)(h + (size_t)N_NODES * OUT_DIM);

    // zero deg_out, deg_in, cursor (row_ptr/partial fully overwritten).
    hipMemsetAsync(deg_out, 0, 2 * N_NODES * sizeof(int), stream);
    hipMemsetAsync(cursor, 0, N_NODES * sizeof(int), stream);

    k_degree<<<(N_EDGES + 255) / 256, 256, 0, stream>>>(src, dst, deg_out, deg_in);

    k_gemm<<<(N_NODES + GEMM_ROWS - 1) / GEMM_ROWS, 256, 0, stream>>>(x, W, deg_out, h);

    k_scan1<<<NBLK, SCAN_BLK, 0, stream>>>(deg_in, row_ptr, partial);
    k_scan2<<<1, 512, 0, stream>>>(partial);
    k_scan3<<<NBLK, SCAN_BLK, 0, stream>>>(row_ptr, partial);

    k_bucket<<<(N_EDGES + 255) / 256, 256, 0, stream>>>(src, dst, row_ptr, cursor, esrc);

    k_gather<<<(N_NODES * 64 + 255) / 256, 256, 0, stream>>>(esrc, row_ptr, deg_in, h, b, out);
}

// Round 4
// 378.007 us; speedup vs baseline: 2.3295x; 1.1153x over previous
//
#include <hip/hip_runtime.h>

#define N_NODES 100000
#define N_EDGES 1600000
#define IN_DIM 256
#define OUT_DIM 32

#define SCAN_BLK 256
#define NBLK ((N_NODES + SCAN_BLK - 1) / SCAN_BLK)   // 391

// ---------------------------------------------------------------------------
// Phase 1: degree computation (int atomics)
// ---------------------------------------------------------------------------
__global__ __launch_bounds__(256) void k_degree(const int* __restrict__ src,
                                                const int* __restrict__ dst,
                                                int* __restrict__ deg_out,
                                                int* __restrict__ deg_in) {
    int i = blockIdx.x * 256 + threadIdx.x;
    if (i < N_EDGES) {
        atomicAdd(&deg_out[src[i]], 1);
        atomicAdd(&deg_in[dst[i]], 1);
    }
}

// ---------------------------------------------------------------------------
// Phase 2: h = (x @ W) * norm_src   [100000,256]x[256,32] -> [100000,32]
// R3 restructure: LDS holds W only (32 KB -> 5 blocks/CU). No barriers in
// the K loop; x streamed per-lane from global (L1/L2 serves the 8x reuse
// across col-groups). Thread tile 4 rows x 4 cols, 16 independent chains.
// norm_src folded into the epilogue.
// ---------------------------------------------------------------------------
__global__ __launch_bounds__(256) void k_gemm(const float* __restrict__ x,
                                              const float* __restrict__ W,
                                              const int* __restrict__ deg_out,
                                              float* __restrict__ h) {
    __shared__ float Wl[IN_DIM][OUT_DIM];  // 32 KB

    const int tid = threadIdx.x;

    // cooperative W load: 2048 float4, 8 per thread, coalesced
    {
        float4* Wl4 = reinterpret_cast<float4*>(&Wl[0][0]);
        const float4* W4 = reinterpret_cast<const float4*>(W);
        #pragma unroll
        for (int i = 0; i < 8; ++i)
            Wl4[tid + i * 256] = W4[tid + i * 256];
    }

    const int rg = tid >> 3;        // 0..31
    const int cg = tid & 7;         // 0..7
    const int row0 = blockIdx.x * 128 + rg * 4;
    const int co = cg * 4;

    // clamped row pointers (last block: duplicate reads of row N-1, no store)
    const float4* xp[4];
    #pragma unroll
    for (int r = 0; r < 4; ++r) {
        int rr = row0 + r;
        if (rr > N_NODES - 1) rr = N_NODES - 1;
        xp[r] = reinterpret_cast<const float4*>(&x[(size_t)rr * IN_DIM]);
    }

    float acc[4][4];
    #pragma unroll
    for (int r = 0; r < 4; ++r)
        #pragma unroll
        for (int c = 0; c < 4; ++c) acc[r][c] = 0.f;

    __syncthreads();  // W ready

    #pragma unroll 4
    for (int k4 = 0; k4 < IN_DIM / 4; ++k4) {
        float4 w0 = *reinterpret_cast<const float4*>(&Wl[k4 * 4 + 0][co]);
        float4 w1 = *reinterpret_cast<const float4*>(&Wl[k4 * 4 + 1][co]);
        float4 w2 = *reinterpret_cast<const float4*>(&Wl[k4 * 4 + 2][co]);
        float4 w3 = *reinterpret_cast<const float4*>(&Wl[k4 * 4 + 3][co]);
        #pragma unroll
        for (int r = 0; r < 4; ++r) {
            float4 xv = xp[r][k4];
            acc[r][0] += xv.x * w0.x + xv.y * w1.x + xv.z * w2.x + xv.w * w3.x;
            acc[r][1] += xv.x * w0.y + xv.y * w1.y + xv.z * w2.y + xv.w * w3.y;
            acc[r][2] += xv.x * w0.z + xv.y * w1.z + xv.z * w2.z + xv.w * w3.z;
            acc[r][3] += xv.x * w0.w + xv.y * w1.w + xv.z * w2.w + xv.w * w3.w;
        }
    }

    #pragma unroll
    for (int r = 0; r < 4; ++r) {
        int grow = row0 + r;
        if (grow < N_NODES) {
            int dg = deg_out[grow];
            float nrm = rsqrtf((float)(dg > 1 ? dg : 1));
            float4 v = make_float4(acc[r][0] * nrm, acc[r][1] * nrm,
                                   acc[r][2] * nrm, acc[r][3] * nrm);
            *reinterpret_cast<float4*>(&h[(size_t)grow * OUT_DIM + co]) = v;
        }
    }
}

// ---------------------------------------------------------------------------
// Phase 3a: exclusive prefix sum of deg_in -> row_ptr (3-kernel scan)
// ---------------------------------------------------------------------------
__global__ __launch_bounds__(SCAN_BLK) void k_scan1(const int* __restrict__ deg_in,
                                                    int* __restrict__ row_ptr,
                                                    int* __restrict__ partial) {
    __shared__ int s[SCAN_BLK];
    int tid = threadIdx.x;
    int i = blockIdx.x * SCAN_BLK + tid;
    int v = (i < N_NODES) ? deg_in[i] : 0;
    s[tid] = v;
    __syncthreads();
    #pragma unroll
    for (int off = 1; off < SCAN_BLK; off <<= 1) {
        int t = (tid >= off) ? s[tid - off] : 0;
        __syncthreads();
        s[tid] += t;
        __syncthreads();
    }
    if (i < N_NODES) row_ptr[i] = s[tid] - v;   // exclusive within block
    if (tid == SCAN_BLK - 1) partial[blockIdx.x] = s[tid];
}

__global__ __launch_bounds__(512) void k_scan2(int* __restrict__ partial) {
    __shared__ int s[512];
    int tid = threadIdx.x;
    int v = (tid < NBLK) ? partial[tid] : 0;
    s[tid] = v;
    __syncthreads();
    #pragma unroll
    for (int off = 1; off < 512; off <<= 1) {
        int t = (tid >= off) ? s[tid - off] : 0;
        __syncthreads();
        s[tid] += t;
        __syncthreads();
    }
    if (tid < NBLK) partial[tid] = s[tid] - v;  // exclusive block offsets
}

__global__ __launch_bounds__(SCAN_BLK) void k_scan3(int* __restrict__ row_ptr,
                                                    const int* __restrict__ partial) {
    int i = blockIdx.x * SCAN_BLK + threadIdx.x;
    if (i < N_NODES) row_ptr[i] += partial[blockIdx.x];
}

// ---------------------------------------------------------------------------
// Phase 3b: bucket edges by dst (counting sort payload = src index)
// ---------------------------------------------------------------------------
__global__ __launch_bounds__(256) void k_bucket(const int* __restrict__ src,
                                                const int* __restrict__ dst,
                                                const int* __restrict__ row_ptr,
                                                int* __restrict__ cursor,
                                                int* __restrict__ esrc) {
    int e = blockIdx.x * 256 + threadIdx.x;
    if (e < N_EDGES) {
        int d = dst[e];
        int pos = row_ptr[d] + atomicAdd(&cursor[d], 1);
        esrc[pos] = src[e];
    }
}

// ---------------------------------------------------------------------------
// Phase 4: pull-based aggregate + finalize (fused)
// ---------------------------------------------------------------------------
__global__ __launch_bounds__(256) void k_gather(const int* __restrict__ esrc,
                                                const int* __restrict__ row_ptr,
                                                const int* __restrict__ deg_in,
                                                const float* __restrict__ h,
                                                const float* __restrict__ bias,
                                                float* __restrict__ out) {
    int wave = (blockIdx.x * 256 + threadIdx.x) >> 6;
    if (wave >= N_NODES) return;
    int lane = threadIdx.x & 63;
    int c = lane & 31;
    int half = lane >> 5;

    int start = row_ptr[wave];
    int deg = deg_in[wave];

    float acc = 0.f;
    for (int j = half; j < deg; j += 2) {
        int s = esrc[start + j];
        acc += h[(size_t)s * OUT_DIM + c];
    }
    acc += __shfl_xor(acc, 32);

    if (half == 0) {
        float nrm = rsqrtf((float)(deg > 1 ? deg : 1));
        out[(size_t)wave * OUT_DIM + c] = acc * nrm + bias[c];
    }
}

// ---------------------------------------------------------------------------
extern "C" void kernel_launch(void* const* d_in, const int* in_sizes, int n_in,
                              void* d_out, int out_size, void* d_ws, size_t ws_size,
                              hipStream_t stream) {
    const float* x   = (const float*)d_in[0];
    const int*   src = (const int*)d_in[1];
    const int*   dst = (const int*)d_in[2];
    const float* W   = (const float*)d_in[3];
    const float* b   = (const float*)d_in[4];
    float* out = (float*)d_out;

    // ws layout (ints): deg_out[N] deg_in[N] row_ptr[N] cursor[N] partial[512]
    //                   then h float[N*32], esrc int[E]
    int* deg_out = (int*)d_ws;
    int* deg_in  = deg_out + N_NODES;
    int* row_ptr = deg_in + N_NODES;
    int* cursor  = row_ptr + N_NODES;
    int* partial = cursor + N_NODES;
    float* h     = (float*)(partial + 512);       // int offset 400512 (16B-aligned)
    int* esrc    = (int*)(h + (size_t)N_NODES * OUT_DIM);

    hipMemsetAsync(deg_out, 0, 2 * N_NODES * sizeof(int), stream);
    hipMemsetAsync(cursor, 0, N_NODES * sizeof(int), stream);

    k_degree<<<(N_EDGES + 255) / 256, 256, 0, stream>>>(src, dst, deg_out, deg_in);

    k_gemm<<<(N_NODES + 127) / 128, 256, 0, stream>>>(x, W, deg_out, h);

    k_scan1<<<NBLK, SCAN_BLK, 0, stream>>>(deg_in, row_ptr, partial);
    k_scan2<<<1, 512, 0, stream>>>(partial);
    k_scan3<<<NBLK, SCAN_BLK, 0, stream>>>(row_ptr, partial);

    k_bucket<<<(N_EDGES + 255) / 256, 256, 0, stream>>>(src, dst, row_ptr, cursor, esrc);

    k_gather<<<(N_NODES * 64 + 255) / 256, 256, 0, stream>>>(esrc, row_ptr, deg_in, h, b, out);
}